// Round 1
// baseline (24318.216 us; speedup 1.0000x reference)
//
#include <hip/hip_runtime.h>
#include <hip/hip_bf16.h>
#include <math.h>

// Problem constants (from reference)
#define B_   4
#define L_   1024
#define D_   1024
#define H_   16
#define NL_  4
#define DH_  64
#define DFF_ 4096
#define EPS_ 1e-5f

// ---------------------------------------------------------------------------
// RMSNorm over D=1024: one block per token, 256 threads x float4.
// Safe in-place (each element read+written by the same thread only).
// ---------------------------------------------------------------------------
__global__ __launch_bounds__(256) void rmsnorm_kernel(
    const float* __restrict__ in, const float* __restrict__ w,
    float* __restrict__ out) {
  int row = blockIdx.x;
  const float4* x4 = (const float4*)(in + (size_t)row * D_);
  float4* y4 = (float4*)(out + (size_t)row * D_);
  const float4* w4 = (const float4*)w;
  int t = threadIdx.x;
  float4 v = x4[t];
  float ss = v.x * v.x + v.y * v.y + v.z * v.z + v.w * v.w;
#pragma unroll
  for (int off = 32; off > 0; off >>= 1) ss += __shfl_down(ss, off, 64);
  __shared__ float red[4];
  if ((t & 63) == 0) red[t >> 6] = ss;
  __syncthreads();
  float tot = red[0] + red[1] + red[2] + red[3];
  float r = rsqrtf(tot * (1.0f / D_) + EPS_);
  float4 wv = w4[t];
  float4 o;
  o.x = v.x * r * wv.x;
  o.y = v.y * r * wv.y;
  o.z = v.z * r * wv.z;
  o.w = v.w * r * wv.w;
  y4[t] = o;
}

// ---------------------------------------------------------------------------
// Per-head RMSNorm(Dh=64) + RoPE, in place on q,k slices of qkv.
// grid (B*L, 8), block 256 = 4 waves; wave w handles pair p = by*4+w
// (p in [0,32): bit4 = is_k, low 4 bits = head). Lane = dim d in [0,64).
// rot=32: pairs (2i,2i+1), freq_i = 10000^(-2i/32), i in [0,16).
// ---------------------------------------------------------------------------
__global__ __launch_bounds__(256) void qknorm_rope_kernel(
    float* __restrict__ qkv, const int* __restrict__ positions,
    const float* __restrict__ qn, const float* __restrict__ kn) {
  int tok = blockIdx.x;  // b*L + l
  int p = blockIdx.y * 4 + (threadIdx.x >> 6);
  int d = threadIdx.x & 63;
  int isK = p >> 4;
  int h = p & 15;
  const float* w = isK ? kn : qn;
  float* ptr = qkv + (size_t)tok * (3 * D_) + (size_t)isK * D_ + h * 64;
  float v = ptr[d];
  float ss = v * v;
#pragma unroll
  for (int off = 1; off < 64; off <<= 1) ss += __shfl_xor(ss, off, 64);
  float r = rsqrtf(ss * (1.0f / 64.0f) + EPS_);
  v = v * r * w[d];
  float pv = __shfl_xor(v, 1, 64);  // partner within rotation pair
  float outv = v;
  if (d < 32) {
    int i = d >> 1;
    float freq = expf(-logf(10000.0f) * (float)(2 * i) * (1.0f / 32.0f));
    float th = (float)positions[tok] * freq;
    float s, c;
    sincosf(th, &s, &c);
    // even lane: t1*c - t2*s ; odd lane: t1*s + t2*c
    outv = (d & 1) ? (pv * s + v * c) : (v * c - pv * s);
  }
  ptr[d] = outv;
}

// ---------------------------------------------------------------------------
// fp32 SGEMM: C[M,N] (op)= A[M,K] @ Bm[K,N], all row-major, M,N %128==0, K%16==0.
// 128x128 tile, BK=16, 256 threads, 8x8 per thread.
// MODE 0: store. MODE 1: C += acc. MODE 2: C = silu(acc) * C.
// ---------------------------------------------------------------------------
template <int MODE>
__global__ __launch_bounds__(256) void gemm_kernel(
    const float* __restrict__ A, const float* __restrict__ Bm,
    float* __restrict__ C, int M, int N, int K) {
  __shared__ float As[16][128];  // As[k][m]
  __shared__ float Bs[16][128];  // Bs[k][n]
  int t = threadIdx.x;
  int m0 = blockIdx.y * 128, n0 = blockIdx.x * 128;
  int tx = t & 15, ty = t >> 4;
  float acc[8][8] = {};
  for (int k0 = 0; k0 < K; k0 += 16) {
    // stage A tile (128 x 16), transposed into As[k][m]
#pragma unroll
    for (int i = 0; i < 2; i++) {
      int f = t + i * 256;       // 0..511 float4s
      int m = f >> 2, q = f & 3;
      float4 v = *(const float4*)(A + (size_t)(m0 + m) * K + k0 + q * 4);
      As[q * 4 + 0][m] = v.x;
      As[q * 4 + 1][m] = v.y;
      As[q * 4 + 2][m] = v.z;
      As[q * 4 + 3][m] = v.w;
    }
    // stage B tile (16 x 128)
#pragma unroll
    for (int i = 0; i < 2; i++) {
      int f = t + i * 256;
      int kk = f >> 5, q = f & 31;
      float4 v = *(const float4*)(Bm + (size_t)(k0 + kk) * N + n0 + q * 4);
      *(float4*)&Bs[kk][q * 4] = v;
    }
    __syncthreads();
#pragma unroll
    for (int kk = 0; kk < 16; kk++) {
      float a[8], b[8];
      *(float4*)&a[0] = *(const float4*)&As[kk][ty * 8];
      *(float4*)&a[4] = *(const float4*)&As[kk][ty * 8 + 4];
      *(float4*)&b[0] = *(const float4*)&Bs[kk][tx * 8];
      *(float4*)&b[4] = *(const float4*)&Bs[kk][tx * 8 + 4];
#pragma unroll
      for (int i = 0; i < 8; i++)
#pragma unroll
        for (int j = 0; j < 8; j++) acc[i][j] += a[i] * b[j];
    }
    __syncthreads();
  }
#pragma unroll
  for (int i = 0; i < 8; i++) {
    float* crow = C + (size_t)(m0 + ty * 8 + i) * N + n0 + tx * 8;
#pragma unroll
    for (int q = 0; q < 2; q++) {
      float4 a = *(float4*)&acc[i][q * 4];
      if (MODE == 0) {
        *(float4*)(crow + q * 4) = a;
      } else if (MODE == 1) {
        float4 prev = *(float4*)(crow + q * 4);
        prev.x += a.x; prev.y += a.y; prev.z += a.z; prev.w += a.w;
        *(float4*)(crow + q * 4) = prev;
      } else {
        float4 prev = *(float4*)(crow + q * 4);
        float4 o;
        o.x = (a.x / (1.0f + expf(-a.x))) * prev.x;
        o.y = (a.y / (1.0f + expf(-a.y))) * prev.y;
        o.z = (a.z / (1.0f + expf(-a.z))) * prev.z;
        o.w = (a.w / (1.0f + expf(-a.w))) * prev.w;
        *(float4*)(crow + q * 4) = o;
      }
    }
  }
}

// ---------------------------------------------------------------------------
// Attention: one block per (b,h,q-row). Scores for all 1024 keys in LDS,
// two-pass softmax, PV split across the 4 waves. q/k are pre-normed+roped
// inside qkv; v is the raw third slice. o layout (B,L,H*Dh) = (B,L,D).
// ---------------------------------------------------------------------------
__global__ __launch_bounds__(256) void attn_kernel(
    const float* __restrict__ qkv, const int* __restrict__ var_id,
    const float* __restrict__ bias_l,  // &bias_emb[layer,0,0], 2*H floats
    float* __restrict__ o) {
  int l = blockIdx.x, h = blockIdx.y, b = blockIdx.z;
  __shared__ __align__(16) float qs[64];
  __shared__ float sc[L_];
  __shared__ float red[8];
  int t = threadIdx.x;
  if (t < 64) qs[t] = qkv[(size_t)(b * L_ + l) * (3 * D_) + h * 64 + t];
  __syncthreads();
  int myvar = var_id[b * L_ + l];
  float b0 = bias_l[h];
  float b1 = bias_l[H_ + h];
  const float scale = 0.125f;  // 1/sqrt(64)
  // scores
  for (int m = t; m < L_; m += 256) {
    const float4* kp =
        (const float4*)(qkv + (size_t)(b * L_ + m) * (3 * D_) + D_ + h * 64);
    const float4* q4 = (const float4*)qs;
    float acc = 0.0f;
#pragma unroll
    for (int j = 0; j < 16; j++) {
      float4 kv = kp[j];
      float4 qv = q4[j];
      acc += qv.x * kv.x + qv.y * kv.y + qv.z * kv.z + qv.w * kv.w;
    }
    sc[m] = acc * scale + ((var_id[b * L_ + m] == myvar) ? b1 : b0);
  }
  __syncthreads();
  // max
  float mx = -INFINITY;
  for (int m = t; m < L_; m += 256) mx = fmaxf(mx, sc[m]);
#pragma unroll
  for (int off = 32; off > 0; off >>= 1) mx = fmaxf(mx, __shfl_down(mx, off, 64));
  if ((t & 63) == 0) red[t >> 6] = mx;
  __syncthreads();
  mx = fmaxf(fmaxf(red[0], red[1]), fmaxf(red[2], red[3]));
  // exp + sum
  float sum = 0.0f;
  for (int m = t; m < L_; m += 256) {
    float e = expf(sc[m] - mx);
    sc[m] = e;
    sum += e;
  }
#pragma unroll
  for (int off = 32; off > 0; off >>= 1) sum += __shfl_down(sum, off, 64);
  if ((t & 63) == 0) red[4 + (t >> 6)] = sum;
  __syncthreads();
  float inv = 1.0f / (red[4] + red[5] + red[6] + red[7]);
  // PV: wave c covers keys [c*256, c*256+256), lane d = output dim
  int c = t >> 6, d = t & 63;
  const float* vb = qkv + 2 * (size_t)D_ + (size_t)h * 64 + d;
  float po = 0.0f;
  int mbase = c * 256;
  for (int m = mbase; m < mbase + 256; m += 4) {
    po += sc[m + 0] * vb[(size_t)(b * L_ + m + 0) * (3 * D_)];
    po += sc[m + 1] * vb[(size_t)(b * L_ + m + 1) * (3 * D_)];
    po += sc[m + 2] * vb[(size_t)(b * L_ + m + 2) * (3 * D_)];
    po += sc[m + 3] * vb[(size_t)(b * L_ + m + 3) * (3 * D_)];
  }
  __shared__ float po_s[4][64];
  po_s[c][d] = po;
  __syncthreads();
  if (t < 64) {
    float r = (po_s[0][t] + po_s[1][t] + po_s[2][t] + po_s[3][t]) * inv;
    o[(size_t)(b * L_ + l) * D_ + h * 64 + t] = r;
  }
}

// ---------------------------------------------------------------------------
extern "C" void kernel_launch(void* const* d_in, const int* in_sizes, int n_in,
                              void* d_out, int out_size, void* d_ws,
                              size_t ws_size, hipStream_t stream) {
  (void)in_sizes; (void)n_in; (void)out_size; (void)ws_size;
  const float* x    = (const float*)d_in[0];
  const int* var_id = (const int*)d_in[1];
  const int* pos    = (const int*)d_in[2];
  const float* Wqkv = (const float*)d_in[3];
  const float* Wo   = (const float*)d_in[4];
  const float* n1   = (const float*)d_in[5];
  const float* n2   = (const float*)d_in[6];
  const float* qn   = (const float*)d_in[7];
  const float* kn   = (const float*)d_in[8];
  const float* be   = (const float*)d_in[9];
  const float* Wg   = (const float*)d_in[10];
  const float* Wu   = (const float*)d_in[11];
  const float* Wd   = (const float*)d_in[12];
  const float* fnw  = (const float*)d_in[13];

  float* h = (float*)d_out;  // residual stream lives in d_out
  const size_t SZ = (size_t)B_ * L_ * D_;  // 4M floats
  float* ws  = (float*)d_ws;
  float* y   = ws;            // SZ floats
  float* qkv = ws + SZ;       // 3*SZ floats
  float* o   = ws + 4 * SZ;   // SZ floats
  float* ff  = ws + 5 * SZ;   // 4*SZ floats  (total 9*SZ = 144 MB)

  hipMemcpyAsync(h, x, SZ * sizeof(float), hipMemcpyDeviceToDevice, stream);

  const int M = B_ * L_;
  for (int l = 0; l < NL_; l++) {
    rmsnorm_kernel<<<M, 256, 0, stream>>>(h, n1 + (size_t)l * D_, y);
    gemm_kernel<0><<<dim3(3 * D_ / 128, M / 128), 256, 0, stream>>>(
        y, Wqkv + (size_t)l * D_ * 3 * D_, qkv, M, 3 * D_, D_);
    qknorm_rope_kernel<<<dim3(M, 8), 256, 0, stream>>>(
        qkv, pos, qn + (size_t)l * DH_, kn + (size_t)l * DH_);
    attn_kernel<<<dim3(L_, H_, B_), 256, 0, stream>>>(
        qkv, var_id, be + (size_t)l * 2 * H_, o);
    gemm_kernel<1><<<dim3(D_ / 128, M / 128), 256, 0, stream>>>(
        o, Wo + (size_t)l * D_ * D_, h, M, D_, D_);
    rmsnorm_kernel<<<M, 256, 0, stream>>>(h, n2 + (size_t)l * D_, y);
    gemm_kernel<0><<<dim3(DFF_ / 128, M / 128), 256, 0, stream>>>(
        y, Wu + (size_t)l * D_ * DFF_, ff, M, DFF_, D_);
    gemm_kernel<2><<<dim3(DFF_ / 128, M / 128), 256, 0, stream>>>(
        y, Wg + (size_t)l * D_ * DFF_, ff, M, DFF_, D_);
    gemm_kernel<1><<<dim3(D_ / 128, M / 128), 256, 0, stream>>>(
        ff, Wd + (size_t)l * DFF_ * D_, h, M, D_, DFF_);
  }
  rmsnorm_kernel<<<M, 256, 0, stream>>>(h, fnw, h);
}

// Round 2
// 13567.560 us; speedup vs baseline: 1.7924x; 1.7924x over previous
//
#include <hip/hip_runtime.h>
#include <hip/hip_bf16.h>
#include <math.h>

// Problem constants (from reference)
#define B_   4
#define L_   1024
#define D_   1024
#define H_   16
#define NL_  4
#define DH_  64
#define DFF_ 4096
#define EPS_ 1e-5f

// ---------------------------------------------------------------------------
// RMSNorm over D=1024: one block per token, 256 threads x float4.
// ---------------------------------------------------------------------------
__global__ __launch_bounds__(256) void rmsnorm_kernel(
    const float* __restrict__ in, const float* __restrict__ w,
    float* __restrict__ out) {
  int row = blockIdx.x;
  const float4* x4 = (const float4*)(in + (size_t)row * D_);
  float4* y4 = (float4*)(out + (size_t)row * D_);
  const float4* w4 = (const float4*)w;
  int t = threadIdx.x;
  float4 v = x4[t];
  float ss = v.x * v.x + v.y * v.y + v.z * v.z + v.w * v.w;
#pragma unroll
  for (int off = 32; off > 0; off >>= 1) ss += __shfl_down(ss, off, 64);
  __shared__ float red[4];
  if ((t & 63) == 0) red[t >> 6] = ss;
  __syncthreads();
  float tot = red[0] + red[1] + red[2] + red[3];
  float r = rsqrtf(tot * (1.0f / D_) + EPS_);
  float4 wv = w4[t];
  float4 o;
  o.x = v.x * r * wv.x;
  o.y = v.y * r * wv.y;
  o.z = v.z * r * wv.z;
  o.w = v.w * r * wv.w;
  y4[t] = o;
}

// ---------------------------------------------------------------------------
// Per-head RMSNorm(Dh=64) + RoPE, in place on q,k slices of qkv.
// ---------------------------------------------------------------------------
__global__ __launch_bounds__(256) void qknorm_rope_kernel(
    float* __restrict__ qkv, const int* __restrict__ positions,
    const float* __restrict__ qn, const float* __restrict__ kn) {
  int tok = blockIdx.x;  // b*L + l
  int p = blockIdx.y * 4 + (threadIdx.x >> 6);
  int d = threadIdx.x & 63;
  int isK = p >> 4;
  int h = p & 15;
  const float* w = isK ? kn : qn;
  float* ptr = qkv + (size_t)tok * (3 * D_) + (size_t)isK * D_ + h * 64;
  float v = ptr[d];
  float ss = v * v;
#pragma unroll
  for (int off = 1; off < 64; off <<= 1) ss += __shfl_xor(ss, off, 64);
  float r = rsqrtf(ss * (1.0f / 64.0f) + EPS_);
  v = v * r * w[d];
  float pv = __shfl_xor(v, 1, 64);  // partner within rotation pair
  float outv = v;
  if (d < 32) {
    int i = d >> 1;
    float freq = expf(-logf(10000.0f) * (float)(2 * i) * (1.0f / 32.0f));
    float th = (float)positions[tok] * freq;
    float s, c;
    sincosf(th, &s, &c);
    outv = (d & 1) ? (pv * s + v * c) : (v * c - pv * s);
  }
  ptr[d] = outv;
}

// ---------------------------------------------------------------------------
// fp32 SGEMM: C[M,N] (op)= A[M,K] @ Bm[K,N], row-major, 128x128 tile, BK=16,
// 256 threads, 8x8 per thread. MODE 0: store. 1: C += acc. 2: C = silu(acc)*C.
// ---------------------------------------------------------------------------
template <int MODE>
__global__ __launch_bounds__(256) void gemm_kernel(
    const float* __restrict__ A, const float* __restrict__ Bm,
    float* __restrict__ C, int M, int N, int K) {
  __shared__ float As[16][128];  // As[k][m]
  __shared__ float Bs[16][128];  // Bs[k][n]
  int t = threadIdx.x;
  int m0 = blockIdx.y * 128, n0 = blockIdx.x * 128;
  int tx = t & 15, ty = t >> 4;
  float acc[8][8] = {};
  for (int k0 = 0; k0 < K; k0 += 16) {
#pragma unroll
    for (int i = 0; i < 2; i++) {
      int f = t + i * 256;
      int m = f >> 2, q = f & 3;
      float4 v = *(const float4*)(A + (size_t)(m0 + m) * K + k0 + q * 4);
      As[q * 4 + 0][m] = v.x;
      As[q * 4 + 1][m] = v.y;
      As[q * 4 + 2][m] = v.z;
      As[q * 4 + 3][m] = v.w;
    }
#pragma unroll
    for (int i = 0; i < 2; i++) {
      int f = t + i * 256;
      int kk = f >> 5, q = f & 31;
      float4 v = *(const float4*)(Bm + (size_t)(k0 + kk) * N + n0 + q * 4);
      *(float4*)&Bs[kk][q * 4] = v;
    }
    __syncthreads();
#pragma unroll
    for (int kk = 0; kk < 16; kk++) {
      float a[8], b[8];
      *(float4*)&a[0] = *(const float4*)&As[kk][ty * 8];
      *(float4*)&a[4] = *(const float4*)&As[kk][ty * 8 + 4];
      *(float4*)&b[0] = *(const float4*)&Bs[kk][tx * 8];
      *(float4*)&b[4] = *(const float4*)&Bs[kk][tx * 8 + 4];
#pragma unroll
      for (int i = 0; i < 8; i++)
#pragma unroll
        for (int j = 0; j < 8; j++) acc[i][j] += a[i] * b[j];
    }
    __syncthreads();
  }
#pragma unroll
  for (int i = 0; i < 8; i++) {
    float* crow = C + (size_t)(m0 + ty * 8 + i) * N + n0 + tx * 8;
#pragma unroll
    for (int q = 0; q < 2; q++) {
      float4 a = *(float4*)&acc[i][q * 4];
      if (MODE == 0) {
        *(float4*)(crow + q * 4) = a;
      } else if (MODE == 1) {
        float4 prev = *(float4*)(crow + q * 4);
        prev.x += a.x; prev.y += a.y; prev.z += a.z; prev.w += a.w;
        *(float4*)(crow + q * 4) = prev;
      } else {
        float4 prev = *(float4*)(crow + q * 4);
        float4 o;
        o.x = (a.x / (1.0f + expf(-a.x))) * prev.x;
        o.y = (a.y / (1.0f + expf(-a.y))) * prev.y;
        o.z = (a.z / (1.0f + expf(-a.z))) * prev.z;
        o.w = (a.w / (1.0f + expf(-a.w))) * prev.w;
        *(float4*)(crow + q * 4) = o;
      }
    }
  }
}

// ---------------------------------------------------------------------------
// Flash-style attention, fp32. Block = 256 threads, handles 64 q-rows of one
// (b,h). Iterates 16 key-tiles of 64; K^T, V, P staged in LDS; 4x4 register
// blocking for both S=Q@K^T and O+=P@V; online softmax (m,l per q-row).
// Thread (ty,tx): ty=t>>4 owns q-rows ty*4..+3; tx=t&15 owns cols tx*4..+3
// (cols = keys for S, dims for O). Lanes sharing ty are 16 consecutive lanes
// -> row reductions via __shfl_xor 1/2/4/8.
// LDS strides padded (65/68) -> only 2-way bank aliasing (free per m136).
// ---------------------------------------------------------------------------
__global__ __launch_bounds__(256) void flash_attn_kernel(
    const float* __restrict__ qkv, const int* __restrict__ var_id,
    const float* __restrict__ bias_l,  // &bias_emb[layer,0,0], 2*H floats
    float* __restrict__ o) {
  __shared__ float Qs[64 * 65];  // [k-dim][q-row]
  __shared__ float Ks[64 * 65];  // [k-dim][key]
  __shared__ float Ps[64 * 65];  // [key][q-row]
  __shared__ float Vs[64 * 68];  // [key][dim]
  __shared__ int vks[64];
  int b = blockIdx.z, h = blockIdx.y, q0 = blockIdx.x * 64;
  int t = threadIdx.x;
  int tx = t & 15, ty = t >> 4;

  // Load Q tile transposed into Qs[d][r]
#pragma unroll
  for (int i = 0; i < 4; i++) {
    int f = t + i * 256;
    int r = f >> 4, dblk = f & 15;
    float4 v = *(const float4*)(qkv + (size_t)(b * L_ + q0 + r) * (3 * D_) +
                                h * 64 + dblk * 4);
    Qs[(dblk * 4 + 0) * 65 + r] = v.x;
    Qs[(dblk * 4 + 1) * 65 + r] = v.y;
    Qs[(dblk * 4 + 2) * 65 + r] = v.z;
    Qs[(dblk * 4 + 3) * 65 + r] = v.w;
  }
  int vq[4];
#pragma unroll
  for (int i = 0; i < 4; i++) vq[i] = var_id[b * L_ + q0 + ty * 4 + i];
  float b0 = bias_l[h], b1 = bias_l[H_ + h];
  const float scale = 0.125f;  // 1/sqrt(64)

  float m_i[4], l_i[4], oacc[4][4];
#pragma unroll
  for (int i = 0; i < 4; i++) {
    m_i[i] = -1e30f;
    l_i[i] = 0.0f;
#pragma unroll
    for (int j = 0; j < 4; j++) oacc[i][j] = 0.0f;
  }
  __syncthreads();

  for (int kt = 0; kt < 16; kt++) {
    int k0 = kt * 64;
    // Stage K^T and V for this tile
#pragma unroll
    for (int i = 0; i < 4; i++) {
      int f = t + i * 256;
      int key = f >> 4, dblk = f & 15;
      size_t base =
          (size_t)(b * L_ + k0 + key) * (3 * D_) + h * 64 + dblk * 4;
      float4 kv = *(const float4*)(qkv + base + D_);
      Ks[(dblk * 4 + 0) * 65 + key] = kv.x;
      Ks[(dblk * 4 + 1) * 65 + key] = kv.y;
      Ks[(dblk * 4 + 2) * 65 + key] = kv.z;
      Ks[(dblk * 4 + 3) * 65 + key] = kv.w;
      float4 vv = *(const float4*)(qkv + base + 2 * D_);
      *(float4*)&Vs[key * 68 + dblk * 4] = vv;
    }
    if (t < 64) vks[t] = var_id[b * L_ + k0 + t];
    __syncthreads();

    // S tile: s[i][j] = sum_d Q[row_i][d] * K[key_j][d]
    float s[4][4] = {};
#pragma unroll 8
    for (int kk = 0; kk < 64; kk++) {
      float a[4], bb[4];
      *(float4*)a = *(const float4*)&Qs[kk * 65 + ty * 4];
      *(float4*)bb = *(const float4*)&Ks[kk * 65 + tx * 4];
#pragma unroll
      for (int i = 0; i < 4; i++)
#pragma unroll
        for (int j = 0; j < 4; j++) s[i][j] += a[i] * bb[j];
    }
    // scale + same-variable bias
#pragma unroll
    for (int i = 0; i < 4; i++)
#pragma unroll
      for (int j = 0; j < 4; j++)
        s[i][j] = s[i][j] * scale + ((vks[tx * 4 + j] == vq[i]) ? b1 : b0);

    // online softmax update
    float alpha[4], rs[4];
#pragma unroll
    for (int i = 0; i < 4; i++) {
      float rm = fmaxf(fmaxf(s[i][0], s[i][1]), fmaxf(s[i][2], s[i][3]));
#pragma unroll
      for (int off = 1; off < 16; off <<= 1)
        rm = fmaxf(rm, __shfl_xor(rm, off, 64));
      float mnew = fmaxf(m_i[i], rm);
      alpha[i] = expf(m_i[i] - mnew);
      m_i[i] = mnew;
      float r = 0.0f;
#pragma unroll
      for (int j = 0; j < 4; j++) {
        float p = expf(s[i][j] - mnew);
        s[i][j] = p;
        r += p;
      }
      rs[i] = r;
    }
#pragma unroll
    for (int i = 0; i < 4; i++) {
#pragma unroll
      for (int off = 1; off < 16; off <<= 1) rs[i] += __shfl_xor(rs[i], off, 64);
      l_i[i] = l_i[i] * alpha[i] + rs[i];
#pragma unroll
      for (int j = 0; j < 4; j++) oacc[i][j] *= alpha[i];
    }
    // publish P tile (transposed: Ps[key][row])
#pragma unroll
    for (int j = 0; j < 4; j++)
#pragma unroll
      for (int i = 0; i < 4; i++) Ps[(tx * 4 + j) * 65 + ty * 4 + i] = s[i][j];
    __syncthreads();

    // O += P @ V
#pragma unroll 8
    for (int kk = 0; kk < 64; kk++) {
      float a[4], bb[4];
      *(float4*)a = *(const float4*)&Ps[kk * 65 + ty * 4];
      *(float4*)bb = *(const float4*)&Vs[kk * 68 + tx * 4];
#pragma unroll
      for (int i = 0; i < 4; i++)
#pragma unroll
        for (int j = 0; j < 4; j++) oacc[i][j] += a[i] * bb[j];
    }
    __syncthreads();
  }

  // epilogue: normalize and store
#pragma unroll
  for (int i = 0; i < 4; i++) {
    float inv = 1.0f / l_i[i];
    float4 v;
    v.x = oacc[i][0] * inv;
    v.y = oacc[i][1] * inv;
    v.z = oacc[i][2] * inv;
    v.w = oacc[i][3] * inv;
    *(float4*)(o + (size_t)(b * L_ + q0 + ty * 4 + i) * D_ + h * 64 +
               tx * 4) = v;
  }
}

// ---------------------------------------------------------------------------
extern "C" void kernel_launch(void* const* d_in, const int* in_sizes, int n_in,
                              void* d_out, int out_size, void* d_ws,
                              size_t ws_size, hipStream_t stream) {
  (void)in_sizes; (void)n_in; (void)out_size; (void)ws_size;
  const float* x    = (const float*)d_in[0];
  const int* var_id = (const int*)d_in[1];
  const int* pos    = (const int*)d_in[2];
  const float* Wqkv = (const float*)d_in[3];
  const float* Wo   = (const float*)d_in[4];
  const float* n1   = (const float*)d_in[5];
  const float* n2   = (const float*)d_in[6];
  const float* qn   = (const float*)d_in[7];
  const float* kn   = (const float*)d_in[8];
  const float* be   = (const float*)d_in[9];
  const float* Wg   = (const float*)d_in[10];
  const float* Wu   = (const float*)d_in[11];
  const float* Wd   = (const float*)d_in[12];
  const float* fnw  = (const float*)d_in[13];

  float* h = (float*)d_out;  // residual stream lives in d_out
  const size_t SZ = (size_t)B_ * L_ * D_;  // 4M floats
  float* ws  = (float*)d_ws;
  float* y   = ws;            // SZ floats
  float* qkv = ws + SZ;       // 3*SZ floats
  float* o   = ws + 4 * SZ;   // SZ floats
  float* ff  = ws + 5 * SZ;   // 4*SZ floats  (total 9*SZ = 144 MB)

  hipMemcpyAsync(h, x, SZ * sizeof(float), hipMemcpyDeviceToDevice, stream);

  const int M = B_ * L_;
  for (int l = 0; l < NL_; l++) {
    rmsnorm_kernel<<<M, 256, 0, stream>>>(h, n1 + (size_t)l * D_, y);
    gemm_kernel<0><<<dim3(3 * D_ / 128, M / 128), 256, 0, stream>>>(
        y, Wqkv + (size_t)l * D_ * 3 * D_, qkv, M, 3 * D_, D_);
    qknorm_rope_kernel<<<dim3(M, 8), 256, 0, stream>>>(
        qkv, pos, qn + (size_t)l * DH_, kn + (size_t)l * DH_);
    flash_attn_kernel<<<dim3(L_ / 64, H_, B_), 256, 0, stream>>>(
        qkv, var_id, be + (size_t)l * 2 * H_, o);
    gemm_kernel<1><<<dim3(D_ / 128, M / 128), 256, 0, stream>>>(
        o, Wo + (size_t)l * D_ * D_, h, M, D_, D_);
    rmsnorm_kernel<<<M, 256, 0, stream>>>(h, n2 + (size_t)l * D_, y);
    gemm_kernel<0><<<dim3(DFF_ / 128, M / 128), 256, 0, stream>>>(
        y, Wu + (size_t)l * D_ * DFF_, ff, M, DFF_, D_);
    gemm_kernel<2><<<dim3(DFF_ / 128, M / 128), 256, 0, stream>>>(
        y, Wg + (size_t)l * D_ * DFF_, ff, M, DFF_, D_);
    gemm_kernel<1><<<dim3(D_ / 128, M / 128), 256, 0, stream>>>(
        ff, Wd + (size_t)l * DFF_ * D_, h, M, D_, DFF_);
  }
  rmsnorm_kernel<<<M, 256, 0, stream>>>(h, fnw, h);
}

// Round 3
// 3357.054 us; speedup vs baseline: 7.2439x; 4.0415x over previous
//
#include <hip/hip_runtime.h>
#include <hip/hip_bf16.h>
#include <math.h>

// Problem constants (from reference)
#define B_   4
#define L_   1024
#define D_   1024
#define H_   16
#define NL_  4
#define DH_  64
#define DFF_ 4096
#define EPS_ 1e-5f

typedef unsigned short u16;
typedef __attribute__((ext_vector_type(8))) short short8;
typedef __attribute__((ext_vector_type(4))) float f32x4;

static __device__ __forceinline__ u16 f2bf(float x) {
  union { float f; unsigned u; } c;
  c.f = x;
  unsigned r = c.u + 0x7fffu + ((c.u >> 16) & 1u);  // RNE
  return (u16)(r >> 16);
}
static __device__ __forceinline__ float bf2f(u16 x) {
  union { unsigned u; float f; } c;
  c.u = ((unsigned)x) << 16;
  return c.f;
}

// ---------------------------------------------------------------------------
// Transpose + cast: W fp32 [R,C] -> Wt bf16 [C,R]. grid (C/64, R/64), 256 thr.
// ---------------------------------------------------------------------------
__global__ __launch_bounds__(256) void transpose_cast_kernel(
    const float* __restrict__ W, u16* __restrict__ Wt, int R, int C) {
  __shared__ float tile[64][65];
  int r0 = blockIdx.y * 64, c0 = blockIdx.x * 64;
  int t = threadIdx.x;
#pragma unroll
  for (int i = 0; i < 4; i++) {
    int f = t + i * 256;
    int rr = f >> 4, c4 = f & 15;
    float4 v = *(const float4*)(W + (size_t)(r0 + rr) * C + c0 + c4 * 4);
    tile[rr][c4 * 4 + 0] = v.x;
    tile[rr][c4 * 4 + 1] = v.y;
    tile[rr][c4 * 4 + 2] = v.z;
    tile[rr][c4 * 4 + 3] = v.w;
  }
  __syncthreads();
#pragma unroll
  for (int i = 0; i < 4; i++) {
    int f = t + i * 256;
    int cc = f >> 4, rq = f & 15;
    unsigned p0 = (unsigned)f2bf(tile[rq * 4 + 0][cc]) |
                  ((unsigned)f2bf(tile[rq * 4 + 1][cc]) << 16);
    unsigned p1 = (unsigned)f2bf(tile[rq * 4 + 2][cc]) |
                  ((unsigned)f2bf(tile[rq * 4 + 3][cc]) << 16);
    uint2 q; q.x = p0; q.y = p1;
    *(uint2*)(Wt + (size_t)(c0 + cc) * R + r0 + rq * 4) = q;
  }
}

// ---------------------------------------------------------------------------
// RMSNorm over D=1024, fp32 out (final norm only).
// ---------------------------------------------------------------------------
__global__ __launch_bounds__(256) void rmsnorm_kernel(
    const float* __restrict__ in, const float* __restrict__ w,
    float* __restrict__ out) {
  int row = blockIdx.x;
  const float4* x4 = (const float4*)(in + (size_t)row * D_);
  float4* y4 = (float4*)(out + (size_t)row * D_);
  const float4* w4 = (const float4*)w;
  int t = threadIdx.x;
  float4 v = x4[t];
  float ss = v.x * v.x + v.y * v.y + v.z * v.z + v.w * v.w;
#pragma unroll
  for (int off = 32; off > 0; off >>= 1) ss += __shfl_down(ss, off, 64);
  __shared__ float red[4];
  if ((t & 63) == 0) red[t >> 6] = ss;
  __syncthreads();
  float tot = red[0] + red[1] + red[2] + red[3];
  float r = rsqrtf(tot * (1.0f / D_) + EPS_);
  float4 wv = w4[t];
  float4 o;
  o.x = v.x * r * wv.x;
  o.y = v.y * r * wv.y;
  o.z = v.z * r * wv.z;
  o.w = v.w * r * wv.w;
  y4[t] = o;
}

// ---------------------------------------------------------------------------
// RMSNorm, bf16 out (layer norms feeding bf16 GEMMs).
// ---------------------------------------------------------------------------
__global__ __launch_bounds__(256) void rmsnorm_bf16_kernel(
    const float* __restrict__ in, const float* __restrict__ w,
    u16* __restrict__ out) {
  int row = blockIdx.x;
  const float4* x4 = (const float4*)(in + (size_t)row * D_);
  const float4* w4 = (const float4*)w;
  int t = threadIdx.x;
  float4 v = x4[t];
  float ss = v.x * v.x + v.y * v.y + v.z * v.z + v.w * v.w;
#pragma unroll
  for (int off = 32; off > 0; off >>= 1) ss += __shfl_down(ss, off, 64);
  __shared__ float red[4];
  if ((t & 63) == 0) red[t >> 6] = ss;
  __syncthreads();
  float tot = red[0] + red[1] + red[2] + red[3];
  float r = rsqrtf(tot * (1.0f / D_) + EPS_);
  float4 wv = w4[t];
  unsigned p0 = (unsigned)f2bf(v.x * r * wv.x) |
                ((unsigned)f2bf(v.y * r * wv.y) << 16);
  unsigned p1 = (unsigned)f2bf(v.z * r * wv.z) |
                ((unsigned)f2bf(v.w * r * wv.w) << 16);
  uint2 q; q.x = p0; q.y = p1;
  *(uint2*)(out + (size_t)row * D_ + t * 4) = q;
}

// ---------------------------------------------------------------------------
// Per-head RMSNorm(Dh=64) + RoPE, in place on q,k slices of qkv (fp32).
// ---------------------------------------------------------------------------
__global__ __launch_bounds__(256) void qknorm_rope_kernel(
    float* __restrict__ qkv, const int* __restrict__ positions,
    const float* __restrict__ qn, const float* __restrict__ kn) {
  int tok = blockIdx.x;  // b*L + l
  int p = blockIdx.y * 4 + (threadIdx.x >> 6);
  int d = threadIdx.x & 63;
  int isK = p >> 4;
  int h = p & 15;
  const float* w = isK ? kn : qn;
  float* ptr = qkv + (size_t)tok * (3 * D_) + (size_t)isK * D_ + h * 64;
  float v = ptr[d];
  float ss = v * v;
#pragma unroll
  for (int off = 1; off < 64; off <<= 1) ss += __shfl_xor(ss, off, 64);
  float r = rsqrtf(ss * (1.0f / 64.0f) + EPS_);
  v = v * r * w[d];
  float pv = __shfl_xor(v, 1, 64);
  float outv = v;
  if (d < 32) {
    int i = d >> 1;
    float freq = expf(-logf(10000.0f) * (float)(2 * i) * (1.0f / 32.0f));
    float th = (float)positions[tok] * freq;
    float s, c;
    sincosf(th, &s, &c);
    outv = (d & 1) ? (pv * s + v * c) : (v * c - pv * s);
  }
  ptr[d] = outv;
}

// ---------------------------------------------------------------------------
// bf16 MFMA GEMM: A [M,K] bf16 row-major, Bt [N,K] bf16 row-major (B^T).
// 128x128 tile, BK=32, 256 threads = 4 waves in 2x2, each wave 64x64 via
// 4x4 grid of 16x16x32 MFMAs. global_load_lds(16B) staging with lane-swizzled
// subtile layout: subtile s (16 rows x 32 k) stored so element (kq,m) sits at
// s*1024B + (kq*16+m)*16B -> fragment ds_read_b128 at (base + lane*16B):
// linear, conflict-free, and identical to the staging lane order.
// MODE 0: C f32 = acc.  MODE 1: C f32 += acc.  MODE 2: C bf16 = acc.
// MODE 3: C bf16 = silu(acc) * C (in place, elementwise).
// ---------------------------------------------------------------------------
template <int MODE>
__global__ __launch_bounds__(256) void gemm_mfma(
    const u16* __restrict__ A, const u16* __restrict__ Bt,
    void* __restrict__ C, int M, int N, int K) {
  __shared__ u16 As[4096];  // 8KB
  __shared__ u16 Bs[4096];  // 8KB
  int t = threadIdx.x;
  int lane = t & 63, wv = t >> 6;
  int wm = wv >> 1, wn = wv & 1;
  int m0 = blockIdx.y * 128, n0 = blockIdx.x * 128;
  int lm = lane & 15, lk = lane >> 4;  // staging: row-in-subtile, 16B k-chunk
  f32x4 acc[4][4];
#pragma unroll
  for (int i = 0; i < 4; i++)
#pragma unroll
    for (int j = 0; j < 4; j++) acc[i][j] = (f32x4)0.0f;

  for (int k0 = 0; k0 < K; k0 += 32) {
#pragma unroll
    for (int i = 0; i < 2; i++) {
      int s = wv * 2 + i;
      const u16* g = A + (size_t)(m0 + s * 16 + lm) * K + k0 + lk * 8;
      __builtin_amdgcn_global_load_lds(
          (const __attribute__((address_space(1))) void*)g,
          (__attribute__((address_space(3))) void*)(As + s * 512), 16, 0, 0);
    }
#pragma unroll
    for (int i = 0; i < 2; i++) {
      int s = wv * 2 + i;
      const u16* g = Bt + (size_t)(n0 + s * 16 + lm) * K + k0 + lk * 8;
      __builtin_amdgcn_global_load_lds(
          (const __attribute__((address_space(1))) void*)g,
          (__attribute__((address_space(3))) void*)(Bs + s * 512), 16, 0, 0);
    }
    __syncthreads();
    short8 a[4], b[4];
#pragma unroll
    for (int i = 0; i < 4; i++)
      a[i] = *(const short8*)(As + (wm * 4 + i) * 512 + lane * 8);
#pragma unroll
    for (int j = 0; j < 4; j++)
      b[j] = *(const short8*)(Bs + (wn * 4 + j) * 512 + lane * 8);
#pragma unroll
    for (int i = 0; i < 4; i++)
#pragma unroll
      for (int j = 0; j < 4; j++)
        acc[i][j] = __builtin_amdgcn_mfma_f32_16x16x32_bf16(
            a[i], b[j], acc[i][j], 0, 0, 0);
    __syncthreads();
  }

  // epilogue: C/D layout col=lane&15, row=(lane>>4)*4+reg
  int rb = (lane >> 4) * 4;
  int cl = lane & 15;
  size_t colbase = (size_t)(n0 + wn * 64 + cl);
#pragma unroll
  for (int i = 0; i < 4; i++) {
#pragma unroll
    for (int r = 0; r < 4; r++) {
      size_t row = (size_t)(m0 + wm * 64 + i * 16 + rb + r);
      if (MODE == 0) {
        float* p = (float*)C + row * N + colbase;
#pragma unroll
        for (int j = 0; j < 4; j++) p[j * 16] = acc[i][j][r];
      } else if (MODE == 1) {
        float* p = (float*)C + row * N + colbase;
#pragma unroll
        for (int j = 0; j < 4; j++) p[j * 16] += acc[i][j][r];
      } else if (MODE == 2) {
        u16* p = (u16*)C + row * N + colbase;
#pragma unroll
        for (int j = 0; j < 4; j++) p[j * 16] = f2bf(acc[i][j][r]);
      } else {
        u16* p = (u16*)C + row * N + colbase;
#pragma unroll
        for (int j = 0; j < 4; j++) {
          float g = acc[i][j][r];
          float u = bf2f(p[j * 16]);
          float sv = g / (1.0f + expf(-g));
          p[j * 16] = f2bf(sv * u);
        }
      }
    }
  }
}

// ---------------------------------------------------------------------------
// Flash-style attention, fp32 compute, bf16 output.
// ---------------------------------------------------------------------------
__global__ __launch_bounds__(256) void flash_attn_kernel(
    const float* __restrict__ qkv, const int* __restrict__ var_id,
    const float* __restrict__ bias_l, u16* __restrict__ o) {
  __shared__ float Qs[64 * 65];  // [k-dim][q-row]
  __shared__ float Ks[64 * 65];  // [k-dim][key]
  __shared__ float Ps[64 * 65];  // [key][q-row]
  __shared__ float Vs[64 * 68];  // [key][dim]
  __shared__ int vks[64];
  int b = blockIdx.z, h = blockIdx.y, q0 = blockIdx.x * 64;
  int t = threadIdx.x;
  int tx = t & 15, ty = t >> 4;

#pragma unroll
  for (int i = 0; i < 4; i++) {
    int f = t + i * 256;
    int r = f >> 4, dblk = f & 15;
    float4 v = *(const float4*)(qkv + (size_t)(b * L_ + q0 + r) * (3 * D_) +
                                h * 64 + dblk * 4);
    Qs[(dblk * 4 + 0) * 65 + r] = v.x;
    Qs[(dblk * 4 + 1) * 65 + r] = v.y;
    Qs[(dblk * 4 + 2) * 65 + r] = v.z;
    Qs[(dblk * 4 + 3) * 65 + r] = v.w;
  }
  int vq[4];
#pragma unroll
  for (int i = 0; i < 4; i++) vq[i] = var_id[b * L_ + q0 + ty * 4 + i];
  float b0 = bias_l[h], b1 = bias_l[H_ + h];
  const float scale = 0.125f;

  float m_i[4], l_i[4], oacc[4][4];
#pragma unroll
  for (int i = 0; i < 4; i++) {
    m_i[i] = -1e30f;
    l_i[i] = 0.0f;
#pragma unroll
    for (int j = 0; j < 4; j++) oacc[i][j] = 0.0f;
  }
  __syncthreads();

  for (int kt = 0; kt < 16; kt++) {
    int k0 = kt * 64;
#pragma unroll
    for (int i = 0; i < 4; i++) {
      int f = t + i * 256;
      int key = f >> 4, dblk = f & 15;
      size_t base = (size_t)(b * L_ + k0 + key) * (3 * D_) + h * 64 + dblk * 4;
      float4 kv = *(const float4*)(qkv + base + D_);
      Ks[(dblk * 4 + 0) * 65 + key] = kv.x;
      Ks[(dblk * 4 + 1) * 65 + key] = kv.y;
      Ks[(dblk * 4 + 2) * 65 + key] = kv.z;
      Ks[(dblk * 4 + 3) * 65 + key] = kv.w;
      float4 vv = *(const float4*)(qkv + base + 2 * D_);
      *(float4*)&Vs[key * 68 + dblk * 4] = vv;
    }
    if (t < 64) vks[t] = var_id[b * L_ + k0 + t];
    __syncthreads();

    float s[4][4] = {};
#pragma unroll 8
    for (int kk = 0; kk < 64; kk++) {
      float a[4], bb[4];
      *(float4*)a = *(const float4*)&Qs[kk * 65 + ty * 4];
      *(float4*)bb = *(const float4*)&Ks[kk * 65 + tx * 4];
#pragma unroll
      for (int i = 0; i < 4; i++)
#pragma unroll
        for (int j = 0; j < 4; j++) s[i][j] += a[i] * bb[j];
    }
#pragma unroll
    for (int i = 0; i < 4; i++)
#pragma unroll
      for (int j = 0; j < 4; j++)
        s[i][j] = s[i][j] * scale + ((vks[tx * 4 + j] == vq[i]) ? b1 : b0);

    float alpha[4], rs[4];
#pragma unroll
    for (int i = 0; i < 4; i++) {
      float rm = fmaxf(fmaxf(s[i][0], s[i][1]), fmaxf(s[i][2], s[i][3]));
#pragma unroll
      for (int off = 1; off < 16; off <<= 1)
        rm = fmaxf(rm, __shfl_xor(rm, off, 64));
      float mnew = fmaxf(m_i[i], rm);
      alpha[i] = expf(m_i[i] - mnew);
      m_i[i] = mnew;
      float r = 0.0f;
#pragma unroll
      for (int j = 0; j < 4; j++) {
        float p = expf(s[i][j] - mnew);
        s[i][j] = p;
        r += p;
      }
      rs[i] = r;
    }
#pragma unroll
    for (int i = 0; i < 4; i++) {
#pragma unroll
      for (int off = 1; off < 16; off <<= 1) rs[i] += __shfl_xor(rs[i], off, 64);
      l_i[i] = l_i[i] * alpha[i] + rs[i];
#pragma unroll
      for (int j = 0; j < 4; j++) oacc[i][j] *= alpha[i];
    }
#pragma unroll
    for (int j = 0; j < 4; j++)
#pragma unroll
      for (int i = 0; i < 4; i++) Ps[(tx * 4 + j) * 65 + ty * 4 + i] = s[i][j];
    __syncthreads();

#pragma unroll 8
    for (int kk = 0; kk < 64; kk++) {
      float a[4], bb[4];
      *(float4*)a = *(const float4*)&Ps[kk * 65 + ty * 4];
      *(float4*)bb = *(const float4*)&Vs[kk * 68 + tx * 4];
#pragma unroll
      for (int i = 0; i < 4; i++)
#pragma unroll
        for (int j = 0; j < 4; j++) oacc[i][j] += a[i] * bb[j];
    }
    __syncthreads();
  }

#pragma unroll
  for (int i = 0; i < 4; i++) {
    float inv = 1.0f / l_i[i];
    unsigned p0 = (unsigned)f2bf(oacc[i][0] * inv) |
                  ((unsigned)f2bf(oacc[i][1] * inv) << 16);
    unsigned p1 = (unsigned)f2bf(oacc[i][2] * inv) |
                  ((unsigned)f2bf(oacc[i][3] * inv) << 16);
    uint2 q; q.x = p0; q.y = p1;
    *(uint2*)(o + (size_t)(b * L_ + q0 + ty * 4 + i) * D_ + h * 64 + tx * 4) =
        q;
  }
}

// ---------------------------------------------------------------------------
extern "C" void kernel_launch(void* const* d_in, const int* in_sizes, int n_in,
                              void* d_out, int out_size, void* d_ws,
                              size_t ws_size, hipStream_t stream) {
  (void)in_sizes; (void)n_in; (void)out_size; (void)ws_size;
  const float* x    = (const float*)d_in[0];
  const int* var_id = (const int*)d_in[1];
  const int* pos    = (const int*)d_in[2];
  const float* Wqkv = (const float*)d_in[3];
  const float* Wo   = (const float*)d_in[4];
  const float* n1   = (const float*)d_in[5];
  const float* n2   = (const float*)d_in[6];
  const float* qn   = (const float*)d_in[7];
  const float* kn   = (const float*)d_in[8];
  const float* be   = (const float*)d_in[9];
  const float* Wg   = (const float*)d_in[10];
  const float* Wu   = (const float*)d_in[11];
  const float* Wd   = (const float*)d_in[12];
  const float* fnw  = (const float*)d_in[13];

  float* h = (float*)d_out;  // residual stream (fp32) lives in d_out
  const size_t MB = 1u << 20;
  char* wsb = (char*)d_ws;
  u16*   y   = (u16*)(wsb);            // 8 MB  [M,D] bf16
  float* qkv = (float*)(wsb + 8*MB);   // 48 MB [M,3D] fp32
  u16*   o   = (u16*)(wsb + 56*MB);    // 8 MB  [M,D] bf16
  u16*   ff  = (u16*)(wsb + 64*MB);    // 32 MB [M,DFF] bf16
  u16*   wT  = (u16*)(wsb + 96*MB);    // ~34 MB per-layer transposed weights
  u16* wqkvT = wT;                        // [3072,1024]
  u16* woT   = wqkvT + (size_t)3072*1024; // [1024,1024]
  u16* wgT   = woT   + (size_t)1024*1024; // [4096,1024]
  u16* wuT   = wgT   + (size_t)4096*1024; // [4096,1024]
  u16* wdT   = wuT   + (size_t)4096*1024; // [1024,4096]

  const size_t SZ = (size_t)B_ * L_ * D_;
  hipMemcpyAsync(h, x, SZ * sizeof(float), hipMemcpyDeviceToDevice, stream);

  const int M = B_ * L_;
  for (int l = 0; l < NL_; l++) {
    // weight prep (bf16, transposed to [N,K])
    transpose_cast_kernel<<<dim3(48, 16), 256, 0, stream>>>(
        Wqkv + (size_t)l * D_ * 3 * D_, wqkvT, D_, 3 * D_);
    transpose_cast_kernel<<<dim3(16, 16), 256, 0, stream>>>(
        Wo + (size_t)l * D_ * D_, woT, D_, D_);
    transpose_cast_kernel<<<dim3(64, 16), 256, 0, stream>>>(
        Wg + (size_t)l * D_ * DFF_, wgT, D_, DFF_);
    transpose_cast_kernel<<<dim3(64, 16), 256, 0, stream>>>(
        Wu + (size_t)l * D_ * DFF_, wuT, D_, DFF_);
    transpose_cast_kernel<<<dim3(16, 64), 256, 0, stream>>>(
        Wd + (size_t)l * DFF_ * D_, wdT, DFF_, D_);

    rmsnorm_bf16_kernel<<<M, 256, 0, stream>>>(h, n1 + (size_t)l * D_, y);
    gemm_mfma<0><<<dim3(3 * D_ / 128, M / 128), 256, 0, stream>>>(
        y, wqkvT, qkv, M, 3 * D_, D_);
    qknorm_rope_kernel<<<dim3(M, 8), 256, 0, stream>>>(
        qkv, pos, qn + (size_t)l * DH_, kn + (size_t)l * DH_);
    flash_attn_kernel<<<dim3(L_ / 64, H_, B_), 256, 0, stream>>>(
        qkv, var_id, be + (size_t)l * 2 * H_, o);
    gemm_mfma<1><<<dim3(D_ / 128, M / 128), 256, 0, stream>>>(
        o, woT, h, M, D_, D_);
    rmsnorm_bf16_kernel<<<M, 256, 0, stream>>>(h, n2 + (size_t)l * D_, y);
    gemm_mfma<2><<<dim3(DFF_ / 128, M / 128), 256, 0, stream>>>(
        y, wuT, ff, M, DFF_, D_);
    gemm_mfma<3><<<dim3(DFF_ / 128, M / 128), 256, 0, stream>>>(
        y, wgT, ff, M, DFF_, D_);
    gemm_mfma<1><<<dim3(D_ / 128, M / 128), 256, 0, stream>>>(
        ff, wdT, h, M, D_, DFF_);
  }
  rmsnorm_kernel<<<M, 256, 0, stream>>>(h, fnw, h);
}

// Round 4
// 2295.299 us; speedup vs baseline: 10.5948x; 1.4626x over previous
//
#include <hip/hip_runtime.h>
#include <hip/hip_bf16.h>
#include <math.h>

// Problem constants (from reference)
#define B_   4
#define L_   1024
#define D_   1024
#define H_   16
#define NL_  4
#define DH_  64
#define DFF_ 4096
#define EPS_ 1e-5f

typedef unsigned short u16;
typedef __attribute__((ext_vector_type(8))) short short8;
typedef __attribute__((ext_vector_type(4))) float f32x4;

static __device__ __forceinline__ u16 f2bf(float x) {
  union { float f; unsigned u; } c;
  c.f = x;
  unsigned r = c.u + 0x7fffu + ((c.u >> 16) & 1u);  // RNE
  return (u16)(r >> 16);
}
static __device__ __forceinline__ float bf2f(u16 x) {
  union { unsigned u; float f; } c;
  c.u = ((unsigned)x) << 16;
  return c.f;
}

// ---------------------------------------------------------------------------
// Transpose + cast: W fp32 [R,C] -> Wt bf16 [C,R]. grid (C/64, R/64), 256 thr.
// ---------------------------------------------------------------------------
__global__ __launch_bounds__(256) void transpose_cast_kernel(
    const float* __restrict__ W, u16* __restrict__ Wt, int R, int C) {
  __shared__ float tile[64][65];
  int r0 = blockIdx.y * 64, c0 = blockIdx.x * 64;
  int t = threadIdx.x;
#pragma unroll
  for (int i = 0; i < 4; i++) {
    int f = t + i * 256;
    int rr = f >> 4, c4 = f & 15;
    float4 v = *(const float4*)(W + (size_t)(r0 + rr) * C + c0 + c4 * 4);
    tile[rr][c4 * 4 + 0] = v.x;
    tile[rr][c4 * 4 + 1] = v.y;
    tile[rr][c4 * 4 + 2] = v.z;
    tile[rr][c4 * 4 + 3] = v.w;
  }
  __syncthreads();
#pragma unroll
  for (int i = 0; i < 4; i++) {
    int f = t + i * 256;
    int cc = f >> 4, rq = f & 15;
    unsigned p0 = (unsigned)f2bf(tile[rq * 4 + 0][cc]) |
                  ((unsigned)f2bf(tile[rq * 4 + 1][cc]) << 16);
    unsigned p1 = (unsigned)f2bf(tile[rq * 4 + 2][cc]) |
                  ((unsigned)f2bf(tile[rq * 4 + 3][cc]) << 16);
    uint2 q; q.x = p0; q.y = p1;
    *(uint2*)(Wt + (size_t)(c0 + cc) * R + r0 + rq * 4) = q;
  }
}

// ---------------------------------------------------------------------------
// RMSNorm over D=1024, fp32 out (final norm only).
// ---------------------------------------------------------------------------
__global__ __launch_bounds__(256) void rmsnorm_kernel(
    const float* __restrict__ in, const float* __restrict__ w,
    float* __restrict__ out) {
  int row = blockIdx.x;
  const float4* x4 = (const float4*)(in + (size_t)row * D_);
  float4* y4 = (float4*)(out + (size_t)row * D_);
  const float4* w4 = (const float4*)w;
  int t = threadIdx.x;
  float4 v = x4[t];
  float ss = v.x * v.x + v.y * v.y + v.z * v.z + v.w * v.w;
#pragma unroll
  for (int off = 32; off > 0; off >>= 1) ss += __shfl_down(ss, off, 64);
  __shared__ float red[4];
  if ((t & 63) == 0) red[t >> 6] = ss;
  __syncthreads();
  float tot = red[0] + red[1] + red[2] + red[3];
  float r = rsqrtf(tot * (1.0f / D_) + EPS_);
  float4 wv = w4[t];
  float4 o;
  o.x = v.x * r * wv.x;
  o.y = v.y * r * wv.y;
  o.z = v.z * r * wv.z;
  o.w = v.w * r * wv.w;
  y4[t] = o;
}

// ---------------------------------------------------------------------------
// RMSNorm, bf16 out (layer norms feeding bf16 GEMMs).
// ---------------------------------------------------------------------------
__global__ __launch_bounds__(256) void rmsnorm_bf16_kernel(
    const float* __restrict__ in, const float* __restrict__ w,
    u16* __restrict__ out) {
  int row = blockIdx.x;
  const float4* x4 = (const float4*)(in + (size_t)row * D_);
  const float4* w4 = (const float4*)w;
  int t = threadIdx.x;
  float4 v = x4[t];
  float ss = v.x * v.x + v.y * v.y + v.z * v.z + v.w * v.w;
#pragma unroll
  for (int off = 32; off > 0; off >>= 1) ss += __shfl_down(ss, off, 64);
  __shared__ float red[4];
  if ((t & 63) == 0) red[t >> 6] = ss;
  __syncthreads();
  float tot = red[0] + red[1] + red[2] + red[3];
  float r = rsqrtf(tot * (1.0f / D_) + EPS_);
  float4 wv = w4[t];
  unsigned p0 = (unsigned)f2bf(v.x * r * wv.x) |
                ((unsigned)f2bf(v.y * r * wv.y) << 16);
  unsigned p1 = (unsigned)f2bf(v.z * r * wv.z) |
                ((unsigned)f2bf(v.w * r * wv.w) << 16);
  uint2 q; q.x = p0; q.y = p1;
  *(uint2*)(out + (size_t)row * D_ + t * 4) = q;
}

// ---------------------------------------------------------------------------
// Per-head RMSNorm(Dh=64) + RoPE, in place on bf16 qkv [M, 3D].
// grid (M, 8), wave handles (isK,head); lane = dim d. fp32 internal math.
// ---------------------------------------------------------------------------
__global__ __launch_bounds__(256) void qknorm_rope_kernel(
    u16* __restrict__ qkv, const int* __restrict__ positions,
    const float* __restrict__ qn, const float* __restrict__ kn) {
  int tok = blockIdx.x;  // b*L + l
  int p = blockIdx.y * 4 + (threadIdx.x >> 6);
  int d = threadIdx.x & 63;
  int isK = p >> 4;
  int h = p & 15;
  const float* w = isK ? kn : qn;
  u16* ptr = qkv + (size_t)tok * (3 * D_) + (size_t)isK * D_ + h * 64;
  float v = bf2f(ptr[d]);
  float ss = v * v;
#pragma unroll
  for (int off = 1; off < 64; off <<= 1) ss += __shfl_xor(ss, off, 64);
  float r = rsqrtf(ss * (1.0f / 64.0f) + EPS_);
  v = v * r * w[d];
  float pv = __shfl_xor(v, 1, 64);
  float outv = v;
  if (d < 32) {
    int i = d >> 1;
    float freq = __expf(-logf(10000.0f) * (float)(2 * i) * (1.0f / 32.0f));
    float th = (float)positions[tok] * freq;
    float s, c;
    __sincosf(th, &s, &c);
    outv = (d & 1) ? (pv * s + v * c) : (v * c - pv * s);
  }
  ptr[d] = f2bf(outv);
}

// ---------------------------------------------------------------------------
// bf16 MFMA GEMM: A [M,K] bf16 row-major, Bt [N,K] bf16 row-major (B^T).
// 128x128 tile, BK=32, 4 waves 2x2, 4x4 grid of 16x16x32 MFMAs per wave.
// MODE 0: C f32 = acc.  MODE 1: C f32 += acc.  MODE 2: C bf16 = acc.
// MODE 3: C bf16 = silu(acc) * C (in place, elementwise).
// ---------------------------------------------------------------------------
template <int MODE>
__global__ __launch_bounds__(256) void gemm_mfma(
    const u16* __restrict__ A, const u16* __restrict__ Bt,
    void* __restrict__ C, int M, int N, int K) {
  __shared__ u16 As[4096];  // 8KB
  __shared__ u16 Bs[4096];  // 8KB
  int t = threadIdx.x;
  int lane = t & 63, wv = t >> 6;
  int wm = wv >> 1, wn = wv & 1;
  int m0 = blockIdx.y * 128, n0 = blockIdx.x * 128;
  int lm = lane & 15, lk = lane >> 4;
  f32x4 acc[4][4];
#pragma unroll
  for (int i = 0; i < 4; i++)
#pragma unroll
    for (int j = 0; j < 4; j++) acc[i][j] = (f32x4)0.0f;

  for (int k0 = 0; k0 < K; k0 += 32) {
#pragma unroll
    for (int i = 0; i < 2; i++) {
      int s = wv * 2 + i;
      const u16* g = A + (size_t)(m0 + s * 16 + lm) * K + k0 + lk * 8;
      __builtin_amdgcn_global_load_lds(
          (const __attribute__((address_space(1))) void*)g,
          (__attribute__((address_space(3))) void*)(As + s * 512), 16, 0, 0);
    }
#pragma unroll
    for (int i = 0; i < 2; i++) {
      int s = wv * 2 + i;
      const u16* g = Bt + (size_t)(n0 + s * 16 + lm) * K + k0 + lk * 8;
      __builtin_amdgcn_global_load_lds(
          (const __attribute__((address_space(1))) void*)g,
          (__attribute__((address_space(3))) void*)(Bs + s * 512), 16, 0, 0);
    }
    __syncthreads();
    short8 a[4], b[4];
#pragma unroll
    for (int i = 0; i < 4; i++)
      a[i] = *(const short8*)(As + (wm * 4 + i) * 512 + lane * 8);
#pragma unroll
    for (int j = 0; j < 4; j++)
      b[j] = *(const short8*)(Bs + (wn * 4 + j) * 512 + lane * 8);
#pragma unroll
    for (int i = 0; i < 4; i++)
#pragma unroll
      for (int j = 0; j < 4; j++)
        acc[i][j] = __builtin_amdgcn_mfma_f32_16x16x32_bf16(
            a[i], b[j], acc[i][j], 0, 0, 0);
    __syncthreads();
  }

  int rb = (lane >> 4) * 4;
  int cl = lane & 15;
  size_t colbase = (size_t)(n0 + wn * 64 + cl);
#pragma unroll
  for (int i = 0; i < 4; i++) {
#pragma unroll
    for (int r = 0; r < 4; r++) {
      size_t row = (size_t)(m0 + wm * 64 + i * 16 + rb + r);
      if (MODE == 0) {
        float* p = (float*)C + row * N + colbase;
#pragma unroll
        for (int j = 0; j < 4; j++) p[j * 16] = acc[i][j][r];
      } else if (MODE == 1) {
        float* p = (float*)C + row * N + colbase;
#pragma unroll
        for (int j = 0; j < 4; j++) p[j * 16] += acc[i][j][r];
      } else if (MODE == 2) {
        u16* p = (u16*)C + row * N + colbase;
#pragma unroll
        for (int j = 0; j < 4; j++) p[j * 16] = f2bf(acc[i][j][r]);
      } else {
        u16* p = (u16*)C + row * N + colbase;
#pragma unroll
        for (int j = 0; j < 4; j++) {
          float g = acc[i][j][r];
          float u = bf2f(p[j * 16]);
          float sv = g / (1.0f + __expf(-g));
          p[j * 16] = f2bf(sv * u);
        }
      }
    }
  }
}

// ---------------------------------------------------------------------------
// MFMA flash attention. Block = 256 thr = 4 waves, one (b,h), 64 q-rows
// (wave w owns 16). K-loop over 16 tiles of 64 keys.
// Q a-frags + K b-frags load directly from global (natural [tok,dim] bf16
// layout matches MFMA fragment order). V^T staged in LDS (stride-72 rows,
// 2-way bank aliasing = free). P round-trips LDS per wave (C->A layout).
// Softmax fp32 in C-frag registers; online m,l per q-row.
// ---------------------------------------------------------------------------
__global__ __launch_bounds__(256) void attn_mfma_kernel(
    const u16* __restrict__ qkv, const int* __restrict__ var_id,
    const float* __restrict__ bias_l, u16* __restrict__ o) {
  __shared__ u16 Ps[4][16 * 72];  // per-wave P [query][key]
  __shared__ u16 Vt[64 * 72];     // V^T [dim][key]
  __shared__ int vks[64];
  int b = blockIdx.z, h = blockIdx.y, q0 = blockIdx.x * 64;
  int t = threadIdx.x, lane = t & 63, w = t >> 6;
  int cl = lane & 15, qd = lane >> 4;
  const size_t ROW = 3 * D_;
  const u16* qbase = qkv + (size_t)(b * L_) * ROW + h * 64;
  const u16* kbase = qbase + D_;
  const u16* vbase = qbase + 2 * D_;
  const float scale = 0.125f;  // 1/sqrt(64)

  // Q a-fragments (K-loop invariant): m=cl, k=qd*8+j
  int qrow = q0 + w * 16 + cl;
  short8 aq0 = *(const short8*)(qbase + (size_t)qrow * ROW + qd * 8);
  short8 aq1 = *(const short8*)(qbase + (size_t)qrow * ROW + 32 + qd * 8);

  int vq[4];
#pragma unroll
  for (int r = 0; r < 4; r++)
    vq[r] = var_id[b * L_ + q0 + w * 16 + qd * 4 + r];
  float b0 = bias_l[h], b1 = bias_l[H_ + h];

  float m_i[4], l_i[4];
  f32x4 oc[4];
#pragma unroll
  for (int r = 0; r < 4; r++) { m_i[r] = -1e30f; l_i[r] = 0.0f; }
#pragma unroll
  for (int ds = 0; ds < 4; ds++) oc[ds] = (f32x4)0.0f;

  // V staging indices: thread handles key pair (2kp,2kp+1), dims g*8..+7
  int kp = t & 31, g = t >> 5;

  for (int kt = 0; kt < 16; kt++) {
    int k0 = kt * 64;
    // stage V^T
    {
      const u16* v0 = vbase + (size_t)(k0 + 2 * kp) * ROW + g * 8;
      short8 va = *(const short8*)v0;
      short8 vb = *(const short8*)(v0 + ROW);
#pragma unroll
      for (int j = 0; j < 8; j++) {
        unsigned pk = (unsigned)(u16)va[j] | ((unsigned)(u16)vb[j] << 16);
        *(unsigned*)&Vt[(g * 8 + j) * 72 + 2 * kp] = pk;
      }
      if (t < 64) vks[t] = var_id[b * L_ + k0 + t];
    }
    __syncthreads();

    // S = Q K^T : 4 key-subtiles x 2 k-steps
    f32x4 s[4];
#pragma unroll
    for (int j = 0; j < 4; j++) {
      const u16* kr = kbase + (size_t)(k0 + j * 16 + cl) * ROW;
      short8 bk0 = *(const short8*)(kr + qd * 8);
      short8 bk1 = *(const short8*)(kr + 32 + qd * 8);
      f32x4 a = (f32x4)0.0f;
      a = __builtin_amdgcn_mfma_f32_16x16x32_bf16(aq0, bk0, a, 0, 0, 0);
      a = __builtin_amdgcn_mfma_f32_16x16x32_bf16(aq1, bk1, a, 0, 0, 0);
      s[j] = a;
    }
    // scale + same-variable bias (C layout: col=cl -> key j*16+cl,
    // row=qd*4+r -> query)
#pragma unroll
    for (int j = 0; j < 4; j++) {
      int kv = vks[j * 16 + cl];
#pragma unroll
      for (int r = 0; r < 4; r++)
        s[j][r] = s[j][r] * scale + ((kv == vq[r]) ? b1 : b0);
    }
    // online softmax per row
#pragma unroll
    for (int r = 0; r < 4; r++) {
      float rm = fmaxf(fmaxf(s[0][r], s[1][r]), fmaxf(s[2][r], s[3][r]));
#pragma unroll
      for (int off = 1; off < 16; off <<= 1)
        rm = fmaxf(rm, __shfl_xor(rm, off, 64));
      float mnew = fmaxf(m_i[r], rm);
      float alpha = __expf(m_i[r] - mnew);
      m_i[r] = mnew;
      float rs = 0.0f;
#pragma unroll
      for (int j = 0; j < 4; j++) {
        float p = __expf(s[j][r] - mnew);
        s[j][r] = p;
        rs += p;
      }
#pragma unroll
      for (int off = 1; off < 16; off <<= 1) rs += __shfl_xor(rs, off, 64);
      l_i[r] = l_i[r] * alpha + rs;
#pragma unroll
      for (int ds = 0; ds < 4; ds++) oc[ds][r] *= alpha;
    }
    // publish P (bf16) to per-wave LDS: [query][key]
#pragma unroll
    for (int j = 0; j < 4; j++)
#pragma unroll
      for (int r = 0; r < 4; r++)
        Ps[w][(qd * 4 + r) * 72 + j * 16 + cl] = f2bf(s[j][r]);

    // O += P V : a-frags from Ps, b-frags = V^T rows from Vt
    short8 ap0 = *(const short8*)(&Ps[w][cl * 72 + qd * 8]);
    short8 ap1 = *(const short8*)(&Ps[w][cl * 72 + 32 + qd * 8]);
#pragma unroll
    for (int ds = 0; ds < 4; ds++) {
      const u16* vr = &Vt[(ds * 16 + cl) * 72];
      short8 bv0 = *(const short8*)(vr + qd * 8);
      short8 bv1 = *(const short8*)(vr + 32 + qd * 8);
      oc[ds] = __builtin_amdgcn_mfma_f32_16x16x32_bf16(ap0, bv0, oc[ds], 0, 0, 0);
      oc[ds] = __builtin_amdgcn_mfma_f32_16x16x32_bf16(ap1, bv1, oc[ds], 0, 0, 0);
    }
    __syncthreads();
  }

  // epilogue: normalize, store bf16 [M, D]
#pragma unroll
  for (int r = 0; r < 4; r++) {
    float inv = 1.0f / l_i[r];
    size_t row = (size_t)(b * L_ + q0 + w * 16 + qd * 4 + r);
#pragma unroll
    for (int ds = 0; ds < 4; ds++)
      o[row * D_ + h * 64 + ds * 16 + cl] = f2bf(oc[ds][r] * inv);
  }
}

// ---------------------------------------------------------------------------
extern "C" void kernel_launch(void* const* d_in, const int* in_sizes, int n_in,
                              void* d_out, int out_size, void* d_ws,
                              size_t ws_size, hipStream_t stream) {
  (void)in_sizes; (void)n_in; (void)out_size; (void)ws_size;
  const float* x    = (const float*)d_in[0];
  const int* var_id = (const int*)d_in[1];
  const int* pos    = (const int*)d_in[2];
  const float* Wqkv = (const float*)d_in[3];
  const float* Wo   = (const float*)d_in[4];
  const float* n1   = (const float*)d_in[5];
  const float* n2   = (const float*)d_in[6];
  const float* qn   = (const float*)d_in[7];
  const float* kn   = (const float*)d_in[8];
  const float* be   = (const float*)d_in[9];
  const float* Wg   = (const float*)d_in[10];
  const float* Wu   = (const float*)d_in[11];
  const float* Wd   = (const float*)d_in[12];
  const float* fnw  = (const float*)d_in[13];

  float* h = (float*)d_out;  // residual stream (fp32) lives in d_out
  const size_t MB = 1u << 20;
  char* wsb = (char*)d_ws;
  u16* y   = (u16*)(wsb);            // 8 MB  [M,D] bf16
  u16* qkv = (u16*)(wsb + 8*MB);     // 16 MB [M,3D] bf16
  u16* o   = (u16*)(wsb + 24*MB);    // 8 MB  [M,D] bf16
  u16* ff  = (u16*)(wsb + 32*MB);    // 32 MB [M,DFF] bf16
  u16* wT  = (u16*)(wsb + 64*MB);    // ~34 MB transposed weights
  u16* wqkvT = wT;                        // [3072,1024]
  u16* woT   = wqkvT + (size_t)3072*1024; // [1024,1024]
  u16* wgT   = woT   + (size_t)1024*1024; // [4096,1024]
  u16* wuT   = wgT   + (size_t)4096*1024; // [4096,1024]
  u16* wdT   = wuT   + (size_t)4096*1024; // [1024,4096]

  const size_t SZ = (size_t)B_ * L_ * D_;
  hipMemcpyAsync(h, x, SZ * sizeof(float), hipMemcpyDeviceToDevice, stream);

  const int M = B_ * L_;
  for (int l = 0; l < NL_; l++) {
    transpose_cast_kernel<<<dim3(48, 16), 256, 0, stream>>>(
        Wqkv + (size_t)l * D_ * 3 * D_, wqkvT, D_, 3 * D_);
    transpose_cast_kernel<<<dim3(16, 16), 256, 0, stream>>>(
        Wo + (size_t)l * D_ * D_, woT, D_, D_);
    transpose_cast_kernel<<<dim3(64, 16), 256, 0, stream>>>(
        Wg + (size_t)l * D_ * DFF_, wgT, D_, DFF_);
    transpose_cast_kernel<<<dim3(64, 16), 256, 0, stream>>>(
        Wu + (size_t)l * D_ * DFF_, wuT, D_, DFF_);
    transpose_cast_kernel<<<dim3(16, 64), 256, 0, stream>>>(
        Wd + (size_t)l * DFF_ * D_, wdT, DFF_, D_);

    rmsnorm_bf16_kernel<<<M, 256, 0, stream>>>(h, n1 + (size_t)l * D_, y);
    gemm_mfma<2><<<dim3(3 * D_ / 128, M / 128), 256, 0, stream>>>(
        y, wqkvT, qkv, M, 3 * D_, D_);
    qknorm_rope_kernel<<<dim3(M, 8), 256, 0, stream>>>(
        qkv, pos, qn + (size_t)l * DH_, kn + (size_t)l * DH_);
    attn_mfma_kernel<<<dim3(L_ / 64, H_, B_), 256, 0, stream>>>(
        qkv, var_id, be + (size_t)l * 2 * H_, o);
    gemm_mfma<1><<<dim3(D_ / 128, M / 128), 256, 0, stream>>>(
        o, woT, h, M, D_, D_);
    rmsnorm_bf16_kernel<<<M, 256, 0, stream>>>(h, n2 + (size_t)l * D_, y);
    gemm_mfma<2><<<dim3(DFF_ / 128, M / 128), 256, 0, stream>>>(
        y, wuT, ff, M, DFF_, D_);
    gemm_mfma<3><<<dim3(DFF_ / 128, M / 128), 256, 0, stream>>>(
        y, wgT, ff, M, DFF_, D_);
    gemm_mfma<1><<<dim3(D_ / 128, M / 128), 256, 0, stream>>>(
        ff, wdT, h, M, D_, DFF_);
  }
  rmsnorm_kernel<<<M, 256, 0, stream>>>(h, fnw, h);
}